// Round 1
// baseline (2210.488 us; speedup 1.0000x reference)
//
#include <hip/hip_runtime.h>
#include <cmath>

#define NN 100000
#define EE 1600000
#define TOTE (EE + NN)

__device__ __forceinline__ float lrelu(float v) { return v > 0.f ? v : 0.2f * v; }

// ---------------- CSR build ----------------
__global__ void init_cnt(int* c) {
    int i = blockIdx.x * blockDim.x + threadIdx.x;
    if (i < NN) c[i] = 1;   // one self-loop per node
}

__global__ void hist_kernel(const int* __restrict__ dst, int* __restrict__ cnt) {
    for (int e = blockIdx.x * blockDim.x + threadIdx.x; e < EE; e += gridDim.x * blockDim.x)
        atomicAdd(&cnt[dst[e]], 1);
}

__global__ __launch_bounds__(1024) void scan_kernel(int* __restrict__ cnt_cursor, int* __restrict__ dst_ptr) {
    __shared__ int sums[1024];
    int t = threadIdx.x;
    const int CH = (NN + 1023) / 1024;   // 98
    int lo = t * CH;
    int hi = lo + CH; if (hi > NN) hi = NN;
    int s = 0;
    for (int i = lo; i < hi; ++i) s += cnt_cursor[i];
    sums[t] = s;
    __syncthreads();
    for (int off = 1; off < 1024; off <<= 1) {
        int v = (t >= off) ? sums[t - off] : 0;
        __syncthreads();
        sums[t] += v;
        __syncthreads();
    }
    int run = (t == 0) ? 0 : sums[t - 1];
    for (int i = lo; i < hi; ++i) {
        int c = cnt_cursor[i];
        dst_ptr[i] = run;
        cnt_cursor[i] = run;   // becomes scatter cursor
        run += c;
    }
    if (t == 0) dst_ptr[NN] = TOTE;
}

__global__ void scatter_kernel(const int* __restrict__ src, const int* __restrict__ dst,
                               int* __restrict__ cursor, int* __restrict__ esrc) {
    for (int e = blockIdx.x * blockDim.x + threadIdx.x; e < TOTE; e += gridDim.x * blockDim.x) {
        int s, d;
        if (e < EE) { s = src[e]; d = dst[e]; }
        else        { s = e - EE; d = s; }          // self-loops appended
        int pos = atomicAdd(&cursor[d], 1);
        esrc[pos] = s;
    }
}

// ---------------- GEMM: H[N,64] = X[N,K] @ W[K,64] ----------------
__global__ __launch_bounds__(256) void gemm_tile(const float* __restrict__ X, const float* __restrict__ W,
                                                 float* __restrict__ H, int K) {
    __shared__ float xs[64][68];
    __shared__ float wt[64][68];   // wt[c][k]
    int t = threadIdx.x;
    int row0 = blockIdx.x * 64;
    int r0 = (t >> 4) << 2;        // 0,4,...,60
    int cb = t & 15;               // cols cb + 16*j
    float acc[4][4] = {{0.f}};
    for (int kc = 0; kc < K; kc += 64) {
        for (int p = 0; p < 4; ++p) {
            int r = p * 16 + (t >> 4);
            int c = (t & 15) * 4;
            int gr = row0 + r;
            float4 v = make_float4(0.f, 0.f, 0.f, 0.f);
            if (gr < NN) v = *(const float4*)(X + (size_t)gr * K + kc + c);
            *(float4*)&xs[r][c] = v;
        }
        for (int p = 0; p < 4; ++p) {
            int k = p * 16 + (t >> 4);
            int c = (t & 15) * 4;
            float4 v = *(const float4*)(W + (size_t)(kc + k) * 64 + c);
            wt[c + 0][k] = v.x; wt[c + 1][k] = v.y; wt[c + 2][k] = v.z; wt[c + 3][k] = v.w;
        }
        __syncthreads();
#pragma unroll
        for (int k4 = 0; k4 < 64; k4 += 4) {
            float4 xv[4], wv[4];
#pragma unroll
            for (int i = 0; i < 4; ++i) xv[i] = *(const float4*)&xs[r0 + i][k4];
#pragma unroll
            for (int j = 0; j < 4; ++j) wv[j] = *(const float4*)&wt[cb + 16 * j][k4];
#pragma unroll
            for (int i = 0; i < 4; ++i)
#pragma unroll
                for (int j = 0; j < 4; ++j)
                    acc[i][j] += xv[i].x * wv[j].x + xv[i].y * wv[j].y +
                                 xv[i].z * wv[j].z + xv[i].w * wv[j].w;
        }
        __syncthreads();
    }
    for (int i = 0; i < 4; ++i) {
        int gr = row0 + r0 + i;
        if (gr < NN)
            for (int j = 0; j < 4; ++j)
                H[(size_t)gr * 64 + cb + 16 * j] = acc[i][j];
    }
}

// ---------------- per-node attention coefficients ----------------
__global__ __launch_bounds__(256) void attn_coeff(const float* __restrict__ h, const float* __restrict__ a_src,
                                                  const float* __restrict__ a_dst, float* __restrict__ asrc,
                                                  float* __restrict__ adst) {
    int n = (blockIdx.x * 256 + threadIdx.x) >> 6;
    if (n >= NN) return;
    int lane = threadIdx.x & 63;          // lane = head*32 + c, matches [H,C] flat
    float v = h[n * 64 + lane];
    float ps = v * a_src[lane];
    float pd = v * a_dst[lane];
    for (int m = 16; m >= 1; m >>= 1) { ps += __shfl_xor(ps, m); pd += __shfl_xor(pd, m); }
    if ((lane & 31) == 0) {
        asrc[2 * n + (lane >> 5)] = ps;
        adst[2 * n + (lane >> 5)] = pd;
    }
}

// ---------------- edge aggregation (64-channel layers) ----------------
// MODE 0: input layer  -> init_out = t, xout = elu(t)
// MODE 1: mid layer    -> xout = elu(t + init_in)
template <int MODE>
__global__ __launch_bounds__(256) void edge_agg(const int* __restrict__ dst_ptr, const int* __restrict__ esrc,
                                                const float* __restrict__ h, const float* __restrict__ asrc,
                                                const float* __restrict__ adst, const float* __restrict__ bias,
                                                const float* __restrict__ init_in, float* __restrict__ init_out,
                                                float* __restrict__ xout) {
    int n = (blockIdx.x * 256 + threadIdx.x) >> 6;
    if (n >= NN) return;
    int lane = threadIdx.x & 63;
    int head = lane >> 5;
    int rs = dst_ptr[n], re = dst_ptr[n + 1];
    float ad0 = adst[2 * n], ad1 = adst[2 * n + 1];
    // pass A: per-head max (lane-parallel over edges)
    float m0 = -1e30f, m1 = -1e30f;
    for (int i = rs + lane; i < re; i += 64) {
        int s = esrc[i];
        m0 = fmaxf(m0, lrelu(asrc[2 * s] + ad0));
        m1 = fmaxf(m1, lrelu(asrc[2 * s + 1] + ad1));
    }
    for (int m = 32; m >= 1; m >>= 1) {
        m0 = fmaxf(m0, __shfl_xor(m0, m));
        m1 = fmaxf(m1, __shfl_xor(m1, m));
    }
    float adh = head ? ad1 : ad0;
    float mh  = head ? m1 : m0;
    // pass B: serial edges; lane j accumulates channel j; every lane tracks its head's l
    float acc = 0.f, l = 0.f;
    for (int i = rs; i < re; ++i) {
        int s = esrc[i];
        float p = __expf(lrelu(asrc[2 * s + head] + adh) - mh);
        l += p;
        acc = fmaf(p, h[s * 64 + lane], acc);
    }
    float t = acc / l + bias[lane];
    if (MODE == 0) {
        init_out[n * 64 + lane] = t;
        xout[n * 64 + lane] = t > 0.f ? t : __expf(t) - 1.f;
    } else {
        t += init_in[n * 64 + lane];
        xout[n * 64 + lane] = t > 0.f ? t : __expf(t) - 1.f;
    }
}

// ---------------- output layer ----------------
__global__ __launch_bounds__(256) void gemm_out_attn(const float* __restrict__ x, const float* __restrict__ Wout,
                                                     const float* __restrict__ a_s, const float* __restrict__ a_d,
                                                     float* __restrict__ h_o, float* __restrict__ asrc_o,
                                                     float* __restrict__ adst_o) {
    int n = (blockIdx.x * 256 + threadIdx.x) >> 6;
    if (n >= NN) return;
    int lane = threadIdx.x & 63;
    float v = x[n * 64 + lane] * Wout[lane];
    for (int m = 32; m >= 1; m >>= 1) v += __shfl_xor(v, m);
    if (lane == 0) {
        h_o[n] = v;
        asrc_o[n] = v * a_s[0];
        adst_o[n] = v * a_d[0];
    }
}

__global__ __launch_bounds__(256) void edge_agg_out(const int* __restrict__ dst_ptr, const int* __restrict__ esrc,
                                                    const float* __restrict__ h_o, const float* __restrict__ asrc_o,
                                                    const float* __restrict__ adst_o, const float* __restrict__ b_out,
                                                    float* __restrict__ out) {
    int n = (blockIdx.x * 256 + threadIdx.x) >> 6;
    if (n >= NN) return;
    int lane = threadIdx.x & 63;
    int rs = dst_ptr[n], re = dst_ptr[n + 1];
    float adv = adst_o[n];
    float m = -1e30f;
    for (int i = rs + lane; i < re; i += 64)
        m = fmaxf(m, lrelu(asrc_o[esrc[i]] + adv));
    for (int mm = 32; mm >= 1; mm >>= 1) m = fmaxf(m, __shfl_xor(m, mm));
    float l = 0.f, acc = 0.f;
    for (int i = rs + lane; i < re; i += 64) {
        int s = esrc[i];
        float p = __expf(lrelu(asrc_o[s] + adv) - m);
        l += p;
        acc = fmaf(p, h_o[s], acc);
    }
    for (int mm = 32; mm >= 1; mm >>= 1) { l += __shfl_xor(l, mm); acc += __shfl_xor(acc, mm); }
    if (lane == 0) out[n] = 1.f / (1.f + __expf(-(acc / l + b_out[0])));
}

// ---------------- launch ----------------
extern "C" void kernel_launch(void* const* d_in, const int* in_sizes, int n_in,
                              void* d_out, int out_size, void* d_ws, size_t ws_size,
                              hipStream_t stream) {
    const float* node_attrs = (const float*)d_in[0];
    const int*   edge_index = (const int*)d_in[1];
    const float* W_in      = (const float*)d_in[2];
    const float* a_src_in  = (const float*)d_in[3];
    const float* a_dst_in  = (const float*)d_in[4];
    const float* b_in      = (const float*)d_in[5];
    const float* W_mid     = (const float*)d_in[6];
    const float* a_src_mid = (const float*)d_in[7];
    const float* a_dst_mid = (const float*)d_in[8];
    const float* b_mid     = (const float*)d_in[9];
    const float* W_out     = (const float*)d_in[10];
    const float* a_src_out = (const float*)d_in[11];
    const float* a_dst_out = (const float*)d_in[12];
    const float* b_out     = (const float*)d_in[13];
    float* out = (float*)d_out;

    const int* srcArr = edge_index;
    const int* dstArr = edge_index + EE;

    char* w = (char*)d_ws;
    auto alloc = [&](size_t bytes) { void* p = (void*)w; w += (bytes + 255) & ~(size_t)255; return p; };
    int*   dst_ptr = (int*)alloc((size_t)(NN + 1) * 4);
    int*   cursor  = (int*)alloc((size_t)NN * 4);
    int*   esrc    = (int*)alloc((size_t)TOTE * 4);
    float* h       = (float*)alloc((size_t)NN * 64 * 4);
    float* asrc    = (float*)alloc((size_t)NN * 2 * 4);
    float* adst    = (float*)alloc((size_t)NN * 2 * 4);
    float* xbuf    = (float*)alloc((size_t)NN * 64 * 4);
    float* ixbuf   = (float*)alloc((size_t)NN * 64 * 4);
    float* h_o     = (float*)alloc((size_t)NN * 4);
    float* asrc_o  = (float*)alloc((size_t)NN * 4);
    float* adst_o  = (float*)alloc((size_t)NN * 4);

    // CSR build (per call; reused by all 8 layers)
    init_cnt<<<(NN + 255) / 256, 256, 0, stream>>>(cursor);
    hist_kernel<<<2048, 256, 0, stream>>>(dstArr, cursor);
    scan_kernel<<<1, 1024, 0, stream>>>(cursor, dst_ptr);
    scatter_kernel<<<2048, 256, 0, stream>>>(srcArr, dstArr, cursor, esrc);

    int gemmBlocks = (NN + 63) / 64;
    int nodeBlocks = (NN + 3) / 4;   // 4 waves (nodes) per 256-thread block

    // input layer
    gemm_tile<<<gemmBlocks, 256, 0, stream>>>(node_attrs, W_in, h, 128);
    attn_coeff<<<nodeBlocks, 256, 0, stream>>>(h, a_src_in, a_dst_in, asrc, adst);
    edge_agg<0><<<nodeBlocks, 256, 0, stream>>>(dst_ptr, esrc, h, asrc, adst, b_in, nullptr, ixbuf, xbuf);

    // 6 mid layers (shared weights)
    for (int l = 0; l < 6; ++l) {
        gemm_tile<<<gemmBlocks, 256, 0, stream>>>(xbuf, W_mid, h, 64);
        attn_coeff<<<nodeBlocks, 256, 0, stream>>>(h, a_src_mid, a_dst_mid, asrc, adst);
        edge_agg<1><<<nodeBlocks, 256, 0, stream>>>(dst_ptr, esrc, h, asrc, adst, b_mid, ixbuf, nullptr, xbuf);
    }

    // output layer
    gemm_out_attn<<<nodeBlocks, 256, 0, stream>>>(xbuf, W_out, a_src_out, a_dst_out, h_o, asrc_o, adst_o);
    edge_agg_out<<<nodeBlocks, 256, 0, stream>>>(dst_ptr, esrc, h_o, asrc_o, adst_o, b_out, out);
}

// Round 2
// 1237.812 us; speedup vs baseline: 1.7858x; 1.7858x over previous
//
#include <hip/hip_runtime.h>
#include <cmath>

#define NN 100000
#define EE 1600000
#define TOTE (EE + NN)
#define NB ((NN + 255) / 256)   // 391 blocks for scan

__device__ __forceinline__ float lrelu(float v) { return v > 0.f ? v : 0.2f * v; }

// ---------------- CSR build ----------------
__global__ void init_cnt(int* c) {
    int i = blockIdx.x * blockDim.x + threadIdx.x;
    if (i < NN) c[i] = 1;   // one self-loop per node
}

__global__ void hist_kernel(const int* __restrict__ dst, int* __restrict__ cnt) {
    for (int e = blockIdx.x * blockDim.x + threadIdx.x; e < EE; e += gridDim.x * blockDim.x)
        atomicAdd(&cnt[dst[e]], 1);
}

// per-block sums of cnt (256 elems/block)
__global__ __launch_bounds__(256) void block_reduce(const int* __restrict__ cnt, int* __restrict__ blkSums) {
    int i = blockIdx.x * 256 + threadIdx.x;
    int v = (i < NN) ? cnt[i] : 0;
    for (int m = 32; m >= 1; m >>= 1) v += __shfl_xor(v, m);
    __shared__ int ws[4];
    if ((threadIdx.x & 63) == 0) ws[threadIdx.x >> 6] = v;
    __syncthreads();
    if (threadIdx.x == 0) blkSums[blockIdx.x] = ws[0] + ws[1] + ws[2] + ws[3];
}

// single-block exclusive scan of the 391 block sums
__global__ __launch_bounds__(512) void scan_blk(int* __restrict__ blkSums) {
    __shared__ int s[512];
    int t = threadIdx.x;
    int v = (t < NB) ? blkSums[t] : 0;
    s[t] = v;
    __syncthreads();
    for (int off = 1; off < 512; off <<= 1) {
        int u = (t >= off) ? s[t - off] : 0;
        __syncthreads();
        s[t] += u;
        __syncthreads();
    }
    if (t < NB) blkSums[t] = s[t] - v;   // exclusive
}

// per-block scan + global offset -> dst_ptr, cursor
__global__ __launch_bounds__(256) void block_scan_out(const int* __restrict__ cnt, const int* __restrict__ blkSums,
                                                      int* __restrict__ dst_ptr, int* __restrict__ cursor) {
    int t = threadIdx.x;
    int i = blockIdx.x * 256 + t;
    int v = (i < NN) ? cnt[i] : 0;
    __shared__ int s[256];
    s[t] = v;
    __syncthreads();
    for (int off = 1; off < 256; off <<= 1) {
        int u = (t >= off) ? s[t - off] : 0;
        __syncthreads();
        s[t] += u;
        __syncthreads();
    }
    if (i < NN) {
        int ex = blkSums[blockIdx.x] + s[t] - v;
        dst_ptr[i] = ex;
        cursor[i] = ex;
    }
    if (i == NN) dst_ptr[NN] = TOTE;
}

__global__ void scatter_kernel(const int* __restrict__ src, const int* __restrict__ dst,
                               int* __restrict__ cursor, int* __restrict__ esrc) {
    for (int e = blockIdx.x * blockDim.x + threadIdx.x; e < TOTE; e += gridDim.x * blockDim.x) {
        int s, d;
        if (e < EE) { s = src[e]; d = dst[e]; }
        else        { s = e - EE; d = s; }          // self-loops appended
        int pos = atomicAdd(&cursor[d], 1);
        esrc[pos] = s;
    }
}

// ---------------- GEMM + fused attention coefficients ----------------
// H[N,64] = X[N,K] @ W[K,64]; asrc[n,h] = sum_c H[n,h*32+c]*a_src[h,c]; same for adst.
__global__ __launch_bounds__(256) void gemm_attn(const float* __restrict__ X, const float* __restrict__ W,
                                                 const float* __restrict__ a_src, const float* __restrict__ a_dst,
                                                 float* __restrict__ H, float* __restrict__ asrc,
                                                 float* __restrict__ adst, int K) {
    __shared__ float xs[64][68];
    __shared__ float wt[64][68];   // wt[c][k]
    int t = threadIdx.x;
    int row0 = blockIdx.x * 64;
    int r0 = (t >> 4) << 2;        // 0,4,...,60
    int cb = t & 15;               // cols cb + 16*j
    float acc[4][4] = {{0.f}};
    for (int kc = 0; kc < K; kc += 64) {
        for (int p = 0; p < 4; ++p) {
            int r = p * 16 + (t >> 4);
            int c = (t & 15) * 4;
            int gr = row0 + r;
            float4 v = make_float4(0.f, 0.f, 0.f, 0.f);
            if (gr < NN) v = *(const float4*)(X + (size_t)gr * K + kc + c);
            *(float4*)&xs[r][c] = v;
        }
        for (int p = 0; p < 4; ++p) {
            int k = p * 16 + (t >> 4);
            int c = (t & 15) * 4;
            float4 v = *(const float4*)(W + (size_t)(kc + k) * 64 + c);
            wt[c + 0][k] = v.x; wt[c + 1][k] = v.y; wt[c + 2][k] = v.z; wt[c + 3][k] = v.w;
        }
        __syncthreads();
#pragma unroll
        for (int k4 = 0; k4 < 64; k4 += 4) {
            float4 xv[4], wv[4];
#pragma unroll
            for (int i = 0; i < 4; ++i) xv[i] = *(const float4*)&xs[r0 + i][k4];
#pragma unroll
            for (int j = 0; j < 4; ++j) wv[j] = *(const float4*)&wt[cb + 16 * j][k4];
#pragma unroll
            for (int i = 0; i < 4; ++i)
#pragma unroll
                for (int j = 0; j < 4; ++j)
                    acc[i][j] += xv[i].x * wv[j].x + xv[i].y * wv[j].y +
                                 xv[i].z * wv[j].z + xv[i].w * wv[j].w;
        }
        __syncthreads();
    }
    // store H
    for (int i = 0; i < 4; ++i) {
        int gr = row0 + r0 + i;
        if (gr < NN)
            for (int j = 0; j < 4; ++j)
                H[(size_t)gr * 64 + cb + 16 * j] = acc[i][j];
    }
    // fused attention-coefficient reduction; reuse xs as red[4][64][17] (4352 floats)
    float asv[4], adv[4];
#pragma unroll
    for (int j = 0; j < 4; ++j) { asv[j] = a_src[cb + 16 * j]; adv[j] = a_dst[cb + 16 * j]; }
    float* red = &xs[0][0];
#pragma unroll
    for (int i = 0; i < 4; ++i) {
        int r = r0 + i;
        // head0 = cols 0..31 (j=0,1), head1 = cols 32..63 (j=2,3)
        red[(0 * 64 + r) * 17 + cb] = acc[i][0] * asv[0] + acc[i][1] * asv[1];
        red[(1 * 64 + r) * 17 + cb] = acc[i][2] * asv[2] + acc[i][3] * asv[3];
        red[(2 * 64 + r) * 17 + cb] = acc[i][0] * adv[0] + acc[i][1] * adv[1];
        red[(3 * 64 + r) * 17 + cb] = acc[i][2] * adv[2] + acc[i][3] * adv[3];
    }
    __syncthreads();
    {
        int q = t >> 6, r = t & 63;
        int gr = row0 + r;
        if (gr < NN) {
            float s = 0.f;
#pragma unroll
            for (int k = 0; k < 16; ++k) s += red[(q * 64 + r) * 17 + k];
            if (q == 0)      asrc[2 * gr + 0] = s;
            else if (q == 1) asrc[2 * gr + 1] = s;
            else if (q == 2) adst[2 * gr + 0] = s;
            else             adst[2 * gr + 1] = s;
        }
    }
}

// ---------------- edge aggregation: single-pass online softmax ----------------
// MODE 0: input layer  -> init_out = t, xout = elu(t)
// MODE 1: mid layer    -> xout = elu(t + init_in)
template <int MODE>
__global__ __launch_bounds__(256) void edge_agg(const int* __restrict__ dst_ptr, const int* __restrict__ esrc,
                                                const float* __restrict__ h, const float* __restrict__ asrc,
                                                const float* __restrict__ adst, const float* __restrict__ bias,
                                                const float* __restrict__ init_in, float* __restrict__ init_out,
                                                float* __restrict__ xout) {
    int n = (blockIdx.x * 256 + threadIdx.x) >> 6;
    if (n >= NN) return;
    int lane = threadIdx.x & 63;
    int head = lane >> 5;
    int rs = dst_ptr[n], re = dst_ptr[n + 1];
    float adh = adst[2 * n + head];
    float m = -1e30f, l = 0.f, acc = 0.f;
    int i = rs;
    for (; i + 4 <= re; i += 4) {
        int s0 = esrc[i], s1 = esrc[i + 1], s2 = esrc[i + 2], s3 = esrc[i + 3];
        float h0 = h[s0 * 64 + lane];
        float h1 = h[s1 * 64 + lane];
        float h2 = h[s2 * 64 + lane];
        float h3 = h[s3 * 64 + lane];
        float e0 = lrelu(asrc[2 * s0 + head] + adh);
        float e1 = lrelu(asrc[2 * s1 + head] + adh);
        float e2 = lrelu(asrc[2 * s2 + head] + adh);
        float e3 = lrelu(asrc[2 * s3 + head] + adh);
        float nm = fmaxf(m, fmaxf(fmaxf(e0, e1), fmaxf(e2, e3)));
        float sc = __expf(m - nm);
        float p0 = __expf(e0 - nm), p1 = __expf(e1 - nm);
        float p2 = __expf(e2 - nm), p3 = __expf(e3 - nm);
        l = l * sc + ((p0 + p1) + (p2 + p3));
        acc = acc * sc + (fmaf(p0, h0, p1 * h1) + fmaf(p2, h2, p3 * h3));
        m = nm;
    }
    for (; i < re; ++i) {
        int s = esrc[i];
        float hv = h[s * 64 + lane];
        float e = lrelu(asrc[2 * s + head] + adh);
        float nm = fmaxf(m, e);
        float sc = __expf(m - nm);
        float p = __expf(e - nm);
        l = l * sc + p;
        acc = acc * sc + p * hv;
        m = nm;
    }
    float t = acc / l + bias[lane];
    if (MODE == 0) {
        init_out[n * 64 + lane] = t;
        xout[n * 64 + lane] = t > 0.f ? t : __expf(t) - 1.f;
    } else {
        t += init_in[n * 64 + lane];
        xout[n * 64 + lane] = t > 0.f ? t : __expf(t) - 1.f;
    }
}

// ---------------- output layer ----------------
__global__ __launch_bounds__(256) void gemm_out_attn(const float* __restrict__ x, const float* __restrict__ Wout,
                                                     const float* __restrict__ a_s, const float* __restrict__ a_d,
                                                     float* __restrict__ h_o, float* __restrict__ asrc_o,
                                                     float* __restrict__ adst_o) {
    int n = (blockIdx.x * 256 + threadIdx.x) >> 6;
    if (n >= NN) return;
    int lane = threadIdx.x & 63;
    float v = x[n * 64 + lane] * Wout[lane];
    for (int m = 32; m >= 1; m >>= 1) v += __shfl_xor(v, m);
    if (lane == 0) {
        h_o[n] = v;
        asrc_o[n] = v * a_s[0];
        adst_o[n] = v * a_d[0];
    }
}

__global__ __launch_bounds__(256) void edge_agg_out(const int* __restrict__ dst_ptr, const int* __restrict__ esrc,
                                                    const float* __restrict__ h_o, const float* __restrict__ asrc_o,
                                                    const float* __restrict__ adst_o, const float* __restrict__ b_out,
                                                    float* __restrict__ out) {
    int n = (blockIdx.x * 256 + threadIdx.x) >> 6;
    if (n >= NN) return;
    int lane = threadIdx.x & 63;
    int rs = dst_ptr[n], re = dst_ptr[n + 1];
    float adv = adst_o[n];
    float m = -1e30f, l = 0.f, acc = 0.f;
    for (int i = rs + lane; i < re; i += 64) {
        int s = esrc[i];
        float e = lrelu(asrc_o[s] + adv);
        float hv = h_o[s];
        float nm = fmaxf(m, e);
        float sc = __expf(m - nm);
        float p = __expf(e - nm);
        l = l * sc + p;
        acc = acc * sc + p * hv;
        m = nm;
    }
    // cross-lane online-softmax merge
    for (int mm = 32; mm >= 1; mm >>= 1) {
        float om = __shfl_xor(m, mm), ol = __shfl_xor(l, mm), oa = __shfl_xor(acc, mm);
        float nm = fmaxf(m, om);
        float s1 = __expf(m - nm), s2 = __expf(om - nm);
        l = l * s1 + ol * s2;
        acc = acc * s1 + oa * s2;
        m = nm;
    }
    if (lane == 0) out[n] = 1.f / (1.f + __expf(-(acc / l + b_out[0])));
}

// ---------------- launch ----------------
extern "C" void kernel_launch(void* const* d_in, const int* in_sizes, int n_in,
                              void* d_out, int out_size, void* d_ws, size_t ws_size,
                              hipStream_t stream) {
    const float* node_attrs = (const float*)d_in[0];
    const int*   edge_index = (const int*)d_in[1];
    const float* W_in      = (const float*)d_in[2];
    const float* a_src_in  = (const float*)d_in[3];
    const float* a_dst_in  = (const float*)d_in[4];
    const float* b_in      = (const float*)d_in[5];
    const float* W_mid     = (const float*)d_in[6];
    const float* a_src_mid = (const float*)d_in[7];
    const float* a_dst_mid = (const float*)d_in[8];
    const float* b_mid     = (const float*)d_in[9];
    const float* W_out     = (const float*)d_in[10];
    const float* a_src_out = (const float*)d_in[11];
    const float* a_dst_out = (const float*)d_in[12];
    const float* b_out     = (const float*)d_in[13];
    float* out = (float*)d_out;

    const int* srcArr = edge_index;
    const int* dstArr = edge_index + EE;

    char* w = (char*)d_ws;
    auto alloc = [&](size_t bytes) { void* p = (void*)w; w += (bytes + 255) & ~(size_t)255; return p; };
    int*   dst_ptr = (int*)alloc((size_t)(NN + 1) * 4);
    int*   cursor  = (int*)alloc((size_t)NN * 4);
    int*   blkSums = (int*)alloc((size_t)512 * 4);
    int*   esrc    = (int*)alloc((size_t)TOTE * 4);
    float* h       = (float*)alloc((size_t)NN * 64 * 4);
    float* asrc    = (float*)alloc((size_t)NN * 2 * 4);
    float* adst    = (float*)alloc((size_t)NN * 2 * 4);
    float* xbuf    = (float*)alloc((size_t)NN * 64 * 4);
    float* ixbuf   = (float*)alloc((size_t)NN * 64 * 4);
    float* h_o     = (float*)alloc((size_t)NN * 4);
    float* asrc_o  = (float*)alloc((size_t)NN * 4);
    float* adst_o  = (float*)alloc((size_t)NN * 4);

    // CSR build (per call; reused by all 8 layers)
    init_cnt<<<NB, 256, 0, stream>>>(cursor);
    hist_kernel<<<2048, 256, 0, stream>>>(dstArr, cursor);
    block_reduce<<<NB, 256, 0, stream>>>(cursor, blkSums);
    scan_blk<<<1, 512, 0, stream>>>(blkSums);
    block_scan_out<<<NB, 256, 0, stream>>>(cursor, blkSums, dst_ptr, cursor);
    scatter_kernel<<<2048, 256, 0, stream>>>(srcArr, dstArr, cursor, esrc);

    int gemmBlocks = (NN + 63) / 64;
    int nodeBlocks = (NN + 3) / 4;   // 4 waves (nodes) per 256-thread block

    // input layer
    gemm_attn<<<gemmBlocks, 256, 0, stream>>>(node_attrs, W_in, a_src_in, a_dst_in, h, asrc, adst, 128);
    edge_agg<0><<<nodeBlocks, 256, 0, stream>>>(dst_ptr, esrc, h, asrc, adst, b_in, nullptr, ixbuf, xbuf);

    // 6 mid layers (shared weights)
    for (int l = 0; l < 6; ++l) {
        gemm_attn<<<gemmBlocks, 256, 0, stream>>>(xbuf, W_mid, a_src_mid, a_dst_mid, h, asrc, adst, 64);
        edge_agg<1><<<nodeBlocks, 256, 0, stream>>>(dst_ptr, esrc, h, asrc, adst, b_mid, ixbuf, nullptr, xbuf);
    }

    // output layer
    gemm_out_attn<<<nodeBlocks, 256, 0, stream>>>(xbuf, W_out, a_src_out, a_dst_out, h_o, asrc_o, adst_o);
    edge_agg_out<<<nodeBlocks, 256, 0, stream>>>(dst_ptr, esrc, h_o, asrc_o, adst_o, b_out, out);
}

// Round 3
// 1058.107 us; speedup vs baseline: 2.0891x; 1.1698x over previous
//
#include <hip/hip_runtime.h>
#include <hip/hip_fp16.h>
#include <cmath>

#define NN 100000
#define EE 1600000
#define TOTE (EE + NN)
#define SHIFT 10
#define NBUK 98          // ceil(NN / 1024)
#define CAPB 18432       // per-bucket region capacity; mean 17408, sd 131 -> +7 sigma

__device__ __forceinline__ float lrelu(float v) { return v > 0.f ? v : 0.2f * v; }

// ---------------- CSR build: 2-phase bucket sort ----------------
// Phase A: bin edges (+self loops) by dst>>10 into 98 bucket regions.
// Each wg reserves a contiguous run per bucket (one global atomic per (wg,bucket)),
// so all global writes land in wg-exclusive ranges -> full-line writebacks.
__global__ __launch_bounds__(256) void binA(const int* __restrict__ src, const int* __restrict__ dst,
                                            int* __restrict__ gcur, int2* __restrict__ region) {
    __shared__ int cnt[NBUK], gbase[NBUK], pos[NBUK];
    int t = threadIdx.x;
    if (t < NBUK) cnt[t] = 0;
    __syncthreads();
    const int CH = (TOTE + gridDim.x - 1) / gridDim.x;
    int lo = blockIdx.x * CH;
    int hi = lo + CH; if (hi > TOTE) hi = TOTE;
    for (int e = lo + t; e < hi; e += 256) {
        int d = (e < EE) ? dst[e] : (e - EE);
        atomicAdd(&cnt[d >> SHIFT], 1);
    }
    __syncthreads();
    if (t < NBUK) {
        gbase[t] = atomicAdd(&gcur[t], cnt[t]);
        pos[t] = 0;
    }
    __syncthreads();
    for (int e = lo + t; e < hi; e += 256) {
        int s, d;
        if (e < EE) { s = src[e]; d = dst[e]; }
        else        { s = e - EE; d = s; }
        int b = d >> SHIFT;
        int k = atomicAdd(&pos[b], 1);
        region[(size_t)b * CAPB + gbase[b] + k] = make_int2(s, d);
    }
}

// tiny exclusive scan of 98 bucket counts
__global__ void scan_buckets(const int* __restrict__ gcur, int* __restrict__ bucketBase) {
    if (threadIdx.x == 0) {
        int run = 0;
        for (int b = 0; b < NBUK; ++b) { bucketBase[b] = run; run += gcur[b]; }
        bucketBase[NBUK] = run;
    }
}

// Phase B: one wg per bucket. Count per node, block-scan -> dst_ptr, then place
// src into the bucket's exclusive esrc segment (L2-absorbed scatter).
__global__ __launch_bounds__(1024) void binB(const int2* __restrict__ region, const int* __restrict__ gcur,
                                             const int* __restrict__ bucketBase,
                                             int* __restrict__ dst_ptr, int* __restrict__ esrc) {
    __shared__ int ncur[1024];
    __shared__ int wsum[16];
    int b = blockIdx.x, t = threadIdx.x;
    int n0 = b << SHIFT;
    int cntE = gcur[b];
    int base = bucketBase[b];
    const int2* reg = region + (size_t)b * CAPB;
    ncur[t] = 0;
    __syncthreads();
    for (int i = t; i < cntE; i += 1024)
        atomicAdd(&ncur[reg[i].y & 1023], 1);
    __syncthreads();
    int v = ncur[t];
    __syncthreads();
    // block exclusive scan of the 1024 per-node counts
    int incl = v;
    for (int off = 1; off < 64; off <<= 1) {
        int u = __shfl_up(incl, off);
        if ((t & 63) >= off) incl += u;
    }
    if ((t & 63) == 63) wsum[t >> 6] = incl;
    __syncthreads();
    if (t < 16) {
        int w = wsum[t];
        int winc = w;
        for (int off = 1; off < 16; off <<= 1) {
            int u = __shfl_up(winc, off);
            if (t >= off) winc += u;
        }
        wsum[t] = winc - w;   // exclusive wave offset
    }
    __syncthreads();
    int excl = incl - v + wsum[t >> 6];
    int n = n0 + t;
    if (n < NN) dst_ptr[n] = base + excl;
    ncur[t] = base + excl;
    __syncthreads();
    for (int i = t; i < cntE; i += 1024) {
        int2 p = reg[i];
        int k = atomicAdd(&ncur[p.y & 1023], 1);
        esrc[k] = p.x;
    }
    if (b == 0 && t == 0) dst_ptr[NN] = TOTE;
}

// ---------------- GEMM + fused attention coefficients ----------------
// H(half)[N,64] = X[N,K] @ W[K,64]; asrc/adst computed from f32 accumulators.
__global__ __launch_bounds__(256) void gemm_attn(const float* __restrict__ X, const float* __restrict__ W,
                                                 const float* __restrict__ a_src, const float* __restrict__ a_dst,
                                                 __half* __restrict__ H, float* __restrict__ asrc,
                                                 float* __restrict__ adst, int K) {
    __shared__ float xs[64][68];
    __shared__ float wt[64][68];   // wt[c][k]
    int t = threadIdx.x;
    int row0 = blockIdx.x * 64;
    int r0 = (t >> 4) << 2;        // 0,4,...,60
    int cb = t & 15;               // cols cb + 16*j
    float acc[4][4] = {{0.f}};
    for (int kc = 0; kc < K; kc += 64) {
        for (int p = 0; p < 4; ++p) {
            int r = p * 16 + (t >> 4);
            int c = (t & 15) * 4;
            int gr = row0 + r;
            float4 v = make_float4(0.f, 0.f, 0.f, 0.f);
            if (gr < NN) v = *(const float4*)(X + (size_t)gr * K + kc + c);
            *(float4*)&xs[r][c] = v;
        }
        for (int p = 0; p < 4; ++p) {
            int k = p * 16 + (t >> 4);
            int c = (t & 15) * 4;
            float4 v = *(const float4*)(W + (size_t)(kc + k) * 64 + c);
            wt[c + 0][k] = v.x; wt[c + 1][k] = v.y; wt[c + 2][k] = v.z; wt[c + 3][k] = v.w;
        }
        __syncthreads();
#pragma unroll
        for (int k4 = 0; k4 < 64; k4 += 4) {
            float4 xv[4], wv[4];
#pragma unroll
            for (int i = 0; i < 4; ++i) xv[i] = *(const float4*)&xs[r0 + i][k4];
#pragma unroll
            for (int j = 0; j < 4; ++j) wv[j] = *(const float4*)&wt[cb + 16 * j][k4];
#pragma unroll
            for (int i = 0; i < 4; ++i)
#pragma unroll
                for (int j = 0; j < 4; ++j)
                    acc[i][j] += xv[i].x * wv[j].x + xv[i].y * wv[j].y +
                                 xv[i].z * wv[j].z + xv[i].w * wv[j].w;
        }
        __syncthreads();
    }
    // store H (fp16)
    for (int i = 0; i < 4; ++i) {
        int gr = row0 + r0 + i;
        if (gr < NN)
            for (int j = 0; j < 4; ++j)
                H[(size_t)gr * 64 + cb + 16 * j] = __float2half(acc[i][j]);
    }
    // fused attention-coefficient reduction; reuse xs as red[4][64][17]
    float asv[4], adv[4];
#pragma unroll
    for (int j = 0; j < 4; ++j) { asv[j] = a_src[cb + 16 * j]; adv[j] = a_dst[cb + 16 * j]; }
    float* red = &xs[0][0];
#pragma unroll
    for (int i = 0; i < 4; ++i) {
        int r = r0 + i;
        red[(0 * 64 + r) * 17 + cb] = acc[i][0] * asv[0] + acc[i][1] * asv[1];
        red[(1 * 64 + r) * 17 + cb] = acc[i][2] * asv[2] + acc[i][3] * asv[3];
        red[(2 * 64 + r) * 17 + cb] = acc[i][0] * adv[0] + acc[i][1] * adv[1];
        red[(3 * 64 + r) * 17 + cb] = acc[i][2] * adv[2] + acc[i][3] * adv[3];
    }
    __syncthreads();
    {
        int q = t >> 6, r = t & 63;
        int gr = row0 + r;
        if (gr < NN) {
            float s = 0.f;
#pragma unroll
            for (int k = 0; k < 16; ++k) s += red[(q * 64 + r) * 17 + k];
            if (q == 0)      asrc[2 * gr + 0] = s;
            else if (q == 1) asrc[2 * gr + 1] = s;
            else if (q == 2) adst[2 * gr + 0] = s;
            else             adst[2 * gr + 1] = s;
        }
    }
}

// ---------------- edge aggregation: single-pass online softmax ----------------
template <int MODE>
__global__ __launch_bounds__(256) void edge_agg(const int* __restrict__ dst_ptr, const int* __restrict__ esrc,
                                                const __half* __restrict__ h, const float* __restrict__ asrc,
                                                const float* __restrict__ adst, const float* __restrict__ bias,
                                                const float* __restrict__ init_in, float* __restrict__ init_out,
                                                float* __restrict__ xout) {
    int n = (blockIdx.x * 256 + threadIdx.x) >> 6;
    if (n >= NN) return;
    int lane = threadIdx.x & 63;
    int head = lane >> 5;
    int rs = dst_ptr[n], re = dst_ptr[n + 1];
    float adh = adst[2 * n + head];
    float m = -1e30f, l = 0.f, acc = 0.f;
    int i = rs;
    for (; i + 4 <= re; i += 4) {
        int s0 = esrc[i], s1 = esrc[i + 1], s2 = esrc[i + 2], s3 = esrc[i + 3];
        float h0 = __half2float(h[s0 * 64 + lane]);
        float h1 = __half2float(h[s1 * 64 + lane]);
        float h2 = __half2float(h[s2 * 64 + lane]);
        float h3 = __half2float(h[s3 * 64 + lane]);
        float e0 = lrelu(asrc[2 * s0 + head] + adh);
        float e1 = lrelu(asrc[2 * s1 + head] + adh);
        float e2 = lrelu(asrc[2 * s2 + head] + adh);
        float e3 = lrelu(asrc[2 * s3 + head] + adh);
        float nm = fmaxf(m, fmaxf(fmaxf(e0, e1), fmaxf(e2, e3)));
        float sc = __expf(m - nm);
        float p0 = __expf(e0 - nm), p1 = __expf(e1 - nm);
        float p2 = __expf(e2 - nm), p3 = __expf(e3 - nm);
        l = l * sc + ((p0 + p1) + (p2 + p3));
        acc = acc * sc + (fmaf(p0, h0, p1 * h1) + fmaf(p2, h2, p3 * h3));
        m = nm;
    }
    for (; i < re; ++i) {
        int s = esrc[i];
        float hv = __half2float(h[s * 64 + lane]);
        float e = lrelu(asrc[2 * s + head] + adh);
        float nm = fmaxf(m, e);
        float sc = __expf(m - nm);
        float p = __expf(e - nm);
        l = l * sc + p;
        acc = acc * sc + p * hv;
        m = nm;
    }
    float t = acc / l + bias[lane];
    if (MODE == 0) {
        init_out[n * 64 + lane] = t;
        xout[n * 64 + lane] = t > 0.f ? t : __expf(t) - 1.f;
    } else {
        t += init_in[n * 64 + lane];
        xout[n * 64 + lane] = t > 0.f ? t : __expf(t) - 1.f;
    }
}

// ---------------- output layer ----------------
__global__ __launch_bounds__(256) void gemm_out_attn(const float* __restrict__ x, const float* __restrict__ Wout,
                                                     const float* __restrict__ a_s, const float* __restrict__ a_d,
                                                     float* __restrict__ h_o, float* __restrict__ asrc_o,
                                                     float* __restrict__ adst_o) {
    int n = (blockIdx.x * 256 + threadIdx.x) >> 6;
    if (n >= NN) return;
    int lane = threadIdx.x & 63;
    float v = x[n * 64 + lane] * Wout[lane];
    for (int m = 32; m >= 1; m >>= 1) v += __shfl_xor(v, m);
    if (lane == 0) {
        h_o[n] = v;
        asrc_o[n] = v * a_s[0];
        adst_o[n] = v * a_d[0];
    }
}

__global__ __launch_bounds__(256) void edge_agg_out(const int* __restrict__ dst_ptr, const int* __restrict__ esrc,
                                                    const float* __restrict__ h_o, const float* __restrict__ asrc_o,
                                                    const float* __restrict__ adst_o, const float* __restrict__ b_out,
                                                    float* __restrict__ out) {
    int n = (blockIdx.x * 256 + threadIdx.x) >> 6;
    if (n >= NN) return;
    int lane = threadIdx.x & 63;
    int rs = dst_ptr[n], re = dst_ptr[n + 1];
    float adv = adst_o[n];
    float m = -1e30f, l = 0.f, acc = 0.f;
    for (int i = rs + lane; i < re; i += 64) {
        int s = esrc[i];
        float e = lrelu(asrc_o[s] + adv);
        float hv = h_o[s];
        float nm = fmaxf(m, e);
        float sc = __expf(m - nm);
        float p = __expf(e - nm);
        l = l * sc + p;
        acc = acc * sc + p * hv;
        m = nm;
    }
    for (int mm = 32; mm >= 1; mm >>= 1) {
        float om = __shfl_xor(m, mm), ol = __shfl_xor(l, mm), oa = __shfl_xor(acc, mm);
        float nm = fmaxf(m, om);
        float s1 = __expf(m - nm), s2 = __expf(om - nm);
        l = l * s1 + ol * s2;
        acc = acc * s1 + oa * s2;
        m = nm;
    }
    if (lane == 0) out[n] = 1.f / (1.f + __expf(-(acc / l + b_out[0])));
}

// ---------------- launch ----------------
extern "C" void kernel_launch(void* const* d_in, const int* in_sizes, int n_in,
                              void* d_out, int out_size, void* d_ws, size_t ws_size,
                              hipStream_t stream) {
    const float* node_attrs = (const float*)d_in[0];
    const int*   edge_index = (const int*)d_in[1];
    const float* W_in      = (const float*)d_in[2];
    const float* a_src_in  = (const float*)d_in[3];
    const float* a_dst_in  = (const float*)d_in[4];
    const float* b_in      = (const float*)d_in[5];
    const float* W_mid     = (const float*)d_in[6];
    const float* a_src_mid = (const float*)d_in[7];
    const float* a_dst_mid = (const float*)d_in[8];
    const float* b_mid     = (const float*)d_in[9];
    const float* W_out     = (const float*)d_in[10];
    const float* a_src_out = (const float*)d_in[11];
    const float* a_dst_out = (const float*)d_in[12];
    const float* b_out     = (const float*)d_in[13];
    float* out = (float*)d_out;

    const int* srcArr = edge_index;
    const int* dstArr = edge_index + EE;

    char* w = (char*)d_ws;
    auto alloc = [&](size_t bytes) { void* p = (void*)w; w += (bytes + 255) & ~(size_t)255; return p; };
    int*   dst_ptr    = (int*)alloc((size_t)(NN + 1) * 4);
    int*   gcur       = (int*)alloc((size_t)NBUK * 4);
    int*   bucketBase = (int*)alloc((size_t)(NBUK + 1) * 4);
    int2*  region     = (int2*)alloc((size_t)NBUK * CAPB * 8);
    int*   esrc       = (int*)alloc((size_t)TOTE * 4);
    __half* h         = (__half*)alloc((size_t)NN * 64 * 2);
    float* asrc       = (float*)alloc((size_t)NN * 2 * 4);
    float* adst       = (float*)alloc((size_t)NN * 2 * 4);
    float* xbuf       = (float*)alloc((size_t)NN * 64 * 4);
    float* ixbuf      = (float*)alloc((size_t)NN * 64 * 4);
    float* h_o        = (float*)alloc((size_t)NN * 4);
    float* asrc_o     = (float*)alloc((size_t)NN * 4);
    float* adst_o     = (float*)alloc((size_t)NN * 4);

    // CSR build: bucket sort (also produces dst_ptr)
    hipMemsetAsync(gcur, 0, NBUK * 4, stream);
    binA<<<256, 256, 0, stream>>>(srcArr, dstArr, gcur, region);
    scan_buckets<<<1, 64, 0, stream>>>(gcur, bucketBase);
    binB<<<NBUK, 1024, 0, stream>>>(region, gcur, bucketBase, dst_ptr, esrc);

    int gemmBlocks = (NN + 63) / 64;
    int nodeBlocks = (NN + 3) / 4;   // 4 waves (nodes) per 256-thread block

    // input layer
    gemm_attn<<<gemmBlocks, 256, 0, stream>>>(node_attrs, W_in, a_src_in, a_dst_in, h, asrc, adst, 128);
    edge_agg<0><<<nodeBlocks, 256, 0, stream>>>(dst_ptr, esrc, h, asrc, adst, b_in, nullptr, ixbuf, xbuf);

    // 6 mid layers (shared weights)
    for (int l = 0; l < 6; ++l) {
        gemm_attn<<<gemmBlocks, 256, 0, stream>>>(xbuf, W_mid, a_src_mid, a_dst_mid, h, asrc, adst, 64);
        edge_agg<1><<<nodeBlocks, 256, 0, stream>>>(dst_ptr, esrc, h, asrc, adst, b_mid, ixbuf, nullptr, xbuf);
    }

    // output layer
    gemm_out_attn<<<nodeBlocks, 256, 0, stream>>>(xbuf, W_out, a_src_out, a_dst_out, h_o, asrc_o, adst_o);
    edge_agg_out<<<nodeBlocks, 256, 0, stream>>>(dst_ptr, esrc, h_o, asrc_o, adst_o, b_out, out);
}

// Round 4
// 845.219 us; speedup vs baseline: 2.6153x; 1.2519x over previous
//
#include <hip/hip_runtime.h>
#include <hip/hip_fp16.h>
#include <cmath>

#define NN 100000
#define EE 1600000
#define TOTE (EE + NN)
#define SHIFT 10
#define NBUK 98          // ceil(NN / 1024)
#define CAPB 18432       // per-bucket region capacity; mean 17408 +7 sigma

typedef _Float16 half8_t __attribute__((ext_vector_type(8)));
typedef _Float16 half4_t __attribute__((ext_vector_type(4)));
typedef float float4_t __attribute__((ext_vector_type(4)));

__device__ __forceinline__ float lrelu(float v) { return v > 0.f ? v : 0.2f * v; }

// ---------------- CSR build: 2-phase bucket sort ----------------
// region entry packed: (src << 10) | (dst & 1023)
__global__ __launch_bounds__(256) void binA(const int* __restrict__ src, const int* __restrict__ dst,
                                            int* __restrict__ gcur, int* __restrict__ region) {
    __shared__ int cnt[NBUK], gbase[NBUK], pos[NBUK];
    int t = threadIdx.x;
    if (t < NBUK) cnt[t] = 0;
    __syncthreads();
    const int CH = (TOTE + gridDim.x - 1) / gridDim.x;
    int lo = blockIdx.x * CH;
    int hi = lo + CH; if (hi > TOTE) hi = TOTE;
    for (int e = lo + t; e < hi; e += 256) {
        int d = (e < EE) ? dst[e] : (e - EE);
        atomicAdd(&cnt[d >> SHIFT], 1);
    }
    __syncthreads();
    if (t < NBUK) {
        gbase[t] = atomicAdd(&gcur[t], cnt[t]);
        pos[t] = 0;
    }
    __syncthreads();
    for (int e = lo + t; e < hi; e += 256) {
        int s, d;
        if (e < EE) { s = src[e]; d = dst[e]; }
        else        { s = e - EE; d = s; }
        int b = d >> SHIFT;
        int k = atomicAdd(&pos[b], 1);
        region[(size_t)b * CAPB + gbase[b] + k] = (s << SHIFT) | (d & 1023);
    }
}

__global__ void scan_buckets(const int* __restrict__ gcur, int* __restrict__ bucketBase) {
    if (threadIdx.x == 0) {
        int run = 0;
        for (int b = 0; b < NBUK; ++b) { bucketBase[b] = run; run += gcur[b]; }
        bucketBase[NBUK] = run;
    }
}

__global__ __launch_bounds__(1024) void binB(const int* __restrict__ region, const int* __restrict__ gcur,
                                             const int* __restrict__ bucketBase,
                                             int* __restrict__ dst_ptr, int* __restrict__ esrc) {
    __shared__ int ncur[1024];
    __shared__ int wsum[16];
    int b = blockIdx.x, t = threadIdx.x;
    int n0 = b << SHIFT;
    int cntE = gcur[b];
    int base = bucketBase[b];
    const int* reg = region + (size_t)b * CAPB;
    ncur[t] = 0;
    __syncthreads();
    for (int i = t; i < cntE; i += 1024)
        atomicAdd(&ncur[reg[i] & 1023], 1);
    __syncthreads();
    int v = ncur[t];
    __syncthreads();
    int incl = v;
    for (int off = 1; off < 64; off <<= 1) {
        int u = __shfl_up(incl, off);
        if ((t & 63) >= off) incl += u;
    }
    if ((t & 63) == 63) wsum[t >> 6] = incl;
    __syncthreads();
    if (t < 16) {
        int w = wsum[t];
        int winc = w;
        for (int off = 1; off < 16; off <<= 1) {
            int u = __shfl_up(winc, off);
            if (t >= off) winc += u;
        }
        wsum[t] = winc - w;
    }
    __syncthreads();
    int excl = incl - v + wsum[t >> 6];
    int n = n0 + t;
    if (n < NN) dst_ptr[n] = base + excl;
    ncur[t] = base + excl;
    __syncthreads();
    for (int i = t; i < cntE; i += 1024) {
        int p = reg[i];
        int k = atomicAdd(&ncur[p & 1023], 1);
        esrc[k] = p >> SHIFT;
    }
    if (b == 0 && t == 0) dst_ptr[NN] = TOTE;
}

// ---------------- f32 -> f16 cast of node_attrs ----------------
__global__ __launch_bounds__(256) void cast_x(const float* __restrict__ in, _Float16* __restrict__ out, int n4) {
    int i = blockIdx.x * 256 + threadIdx.x;
    if (i >= n4) return;
    float4 v = ((const float4*)in)[i];
    half4_t h = { (_Float16)v.x, (_Float16)v.y, (_Float16)v.z, (_Float16)v.w };
    *(half4_t*)(out + 4 * (size_t)i) = h;
}

// ---------------- MFMA GEMM + fused attention coefficients ----------------
// H(f16)[N,64] = X(f16)[N,K] @ W(f32)[K,64]; asrc/adst from f32 accumulators.
// Block: 64 rows, 4 waves x 16 rows. Wave: 4 col-tiles of 16, K/32 mfma steps.
template <int K>
__global__ __launch_bounds__(256) void gemm_attn(const _Float16* __restrict__ X, const float* __restrict__ W,
                                                 const float* __restrict__ a_src, const float* __restrict__ a_dst,
                                                 _Float16* __restrict__ H, float* __restrict__ asrc,
                                                 float* __restrict__ adst) {
    __shared__ _Float16 wt[64][K + 8];    // wt[n][k], padded stride
    int t = threadIdx.x;
    // stage W transposed to f16
    for (int it = 0; it < K / 16; ++it) {
        int idx4 = it * 256 + t;          // float4 index into W
        int k = idx4 >> 4;
        int n4 = (idx4 * 4) & 63;
        float4 v = *(const float4*)(W + (size_t)idx4 * 4);
        wt[n4 + 0][k] = (_Float16)v.x;
        wt[n4 + 1][k] = (_Float16)v.y;
        wt[n4 + 2][k] = (_Float16)v.z;
        wt[n4 + 3][k] = (_Float16)v.w;
    }
    __syncthreads();

    int row0 = blockIdx.x * 64;
    int wr = (t >> 6) * 16;               // wave row offset
    int lane = t & 63;
    int m = lane & 15;
    int q = lane >> 4;

    int rowA = row0 + wr + m;
    if (rowA >= NN) rowA = NN - 1;        // clamp (stores guarded)
    const _Float16* xrow = X + (size_t)rowA * K + q * 8;

    float4_t acc[4] = { {0,0,0,0}, {0,0,0,0}, {0,0,0,0}, {0,0,0,0} };
#pragma unroll
    for (int kc = 0; kc < K / 32; ++kc) {
        half8_t av = *(const half8_t*)(xrow + kc * 32);
#pragma unroll
        for (int c = 0; c < 4; ++c) {
            half8_t bv = *(const half8_t*)&wt[c * 16 + m][kc * 32 + q * 8];
            acc[c] = __builtin_amdgcn_mfma_f32_16x16x32_f16(av, bv, acc[c], 0, 0, 0);
        }
    }

    // store H (f16): D row = wr + q*4 + reg, col = c*16 + m
#pragma unroll
    for (int r = 0; r < 4; ++r) {
        int row = row0 + wr + q * 4 + r;
        if (row < NN) {
#pragma unroll
            for (int c = 0; c < 4; ++c)
                H[(size_t)row * 64 + c * 16 + m] = (_Float16)acc[c][r];
        }
    }

    // fused asrc/adst: per row, reduce over the 16 lanes of the quad
    float as0 = a_src[m], as1 = a_src[16 + m], as2 = a_src[32 + m], as3 = a_src[48 + m];
    float ad0 = a_dst[m], ad1 = a_dst[16 + m], ad2 = a_dst[32 + m], ad3 = a_dst[48 + m];
#pragma unroll
    for (int r = 0; r < 4; ++r) {
        float s0 = acc[0][r] * as0 + acc[1][r] * as1;   // head0 src
        float s1 = acc[2][r] * as2 + acc[3][r] * as3;   // head1 src
        float d0 = acc[0][r] * ad0 + acc[1][r] * ad1;
        float d1 = acc[2][r] * ad2 + acc[3][r] * ad3;
#pragma unroll
        for (int mk = 1; mk < 16; mk <<= 1) {
            s0 += __shfl_xor(s0, mk);
            s1 += __shfl_xor(s1, mk);
            d0 += __shfl_xor(d0, mk);
            d1 += __shfl_xor(d1, mk);
        }
        int row = row0 + wr + q * 4 + r;
        if (m == 0 && row < NN) {
            asrc[2 * row + 0] = s0;
            asrc[2 * row + 1] = s1;
            adst[2 * row + 0] = d0;
            adst[2 * row + 1] = d1;
        }
    }
}

// ---------------- edge aggregation: single-pass online softmax ----------------
template <int MODE>
__global__ __launch_bounds__(256) void edge_agg(const int* __restrict__ dst_ptr, const int* __restrict__ esrc,
                                                const _Float16* __restrict__ h, const float* __restrict__ asrc,
                                                const float* __restrict__ adst, const float* __restrict__ bias,
                                                const float* __restrict__ init_in, float* __restrict__ init_out,
                                                _Float16* __restrict__ xout) {
    int n = (blockIdx.x * 256 + threadIdx.x) >> 6;
    if (n >= NN) return;
    int lane = threadIdx.x & 63;
    int head = lane >> 5;
    int rs = dst_ptr[n], re = dst_ptr[n + 1];
    float adh = adst[2 * n + head];
    float m = -1e30f, l = 0.f, acc = 0.f;
    int i = rs;
    for (; i + 4 <= re; i += 4) {
        int s0 = esrc[i], s1 = esrc[i + 1], s2 = esrc[i + 2], s3 = esrc[i + 3];
        float h0 = (float)h[s0 * 64 + lane];
        float h1 = (float)h[s1 * 64 + lane];
        float h2 = (float)h[s2 * 64 + lane];
        float h3 = (float)h[s3 * 64 + lane];
        float e0 = lrelu(asrc[2 * s0 + head] + adh);
        float e1 = lrelu(asrc[2 * s1 + head] + adh);
        float e2 = lrelu(asrc[2 * s2 + head] + adh);
        float e3 = lrelu(asrc[2 * s3 + head] + adh);
        float nm = fmaxf(m, fmaxf(fmaxf(e0, e1), fmaxf(e2, e3)));
        float sc = __expf(m - nm);
        float p0 = __expf(e0 - nm), p1 = __expf(e1 - nm);
        float p2 = __expf(e2 - nm), p3 = __expf(e3 - nm);
        l = l * sc + ((p0 + p1) + (p2 + p3));
        acc = acc * sc + (fmaf(p0, h0, p1 * h1) + fmaf(p2, h2, p3 * h3));
        m = nm;
    }
    for (; i < re; ++i) {
        int s = esrc[i];
        float hv = (float)h[s * 64 + lane];
        float e = lrelu(asrc[2 * s + head] + adh);
        float nm = fmaxf(m, e);
        float sc = __expf(m - nm);
        float p = __expf(e - nm);
        l = l * sc + p;
        acc = acc * sc + p * hv;
        m = nm;
    }
    float t = acc / l + bias[lane];
    if (MODE == 0) {
        init_out[n * 64 + lane] = t;
        xout[n * 64 + lane] = (_Float16)(t > 0.f ? t : __expf(t) - 1.f);
    } else {
        t += init_in[n * 64 + lane];
        xout[n * 64 + lane] = (_Float16)(t > 0.f ? t : __expf(t) - 1.f);
    }
}

// ---------------- output layer ----------------
__global__ __launch_bounds__(256) void gemm_out_attn(const _Float16* __restrict__ x, const float* __restrict__ Wout,
                                                     const float* __restrict__ a_s, const float* __restrict__ a_d,
                                                     float* __restrict__ h_o, float* __restrict__ asrc_o,
                                                     float* __restrict__ adst_o) {
    int n = (blockIdx.x * 256 + threadIdx.x) >> 6;
    if (n >= NN) return;
    int lane = threadIdx.x & 63;
    float v = (float)x[n * 64 + lane] * Wout[lane];
    for (int m = 32; m >= 1; m >>= 1) v += __shfl_xor(v, m);
    if (lane == 0) {
        h_o[n] = v;
        asrc_o[n] = v * a_s[0];
        adst_o[n] = v * a_d[0];
    }
}

__global__ __launch_bounds__(256) void edge_agg_out(const int* __restrict__ dst_ptr, const int* __restrict__ esrc,
                                                    const float* __restrict__ h_o, const float* __restrict__ asrc_o,
                                                    const float* __restrict__ adst_o, const float* __restrict__ b_out,
                                                    float* __restrict__ out) {
    int n = (blockIdx.x * 256 + threadIdx.x) >> 6;
    if (n >= NN) return;
    int lane = threadIdx.x & 63;
    int rs = dst_ptr[n], re = dst_ptr[n + 1];
    float adv = adst_o[n];
    float m = -1e30f, l = 0.f, acc = 0.f;
    for (int i = rs + lane; i < re; i += 64) {
        int s = esrc[i];
        float e = lrelu(asrc_o[s] + adv);
        float hv = h_o[s];
        float nm = fmaxf(m, e);
        float sc = __expf(m - nm);
        float p = __expf(e - nm);
        l = l * sc + p;
        acc = acc * sc + p * hv;
        m = nm;
    }
    for (int mm = 32; mm >= 1; mm >>= 1) {
        float om = __shfl_xor(m, mm), ol = __shfl_xor(l, mm), oa = __shfl_xor(acc, mm);
        float nm = fmaxf(m, om);
        float s1 = __expf(m - nm), s2 = __expf(om - nm);
        l = l * s1 + ol * s2;
        acc = acc * s1 + oa * s2;
        m = nm;
    }
    if (lane == 0) out[n] = 1.f / (1.f + __expf(-(acc / l + b_out[0])));
}

// ---------------- launch ----------------
extern "C" void kernel_launch(void* const* d_in, const int* in_sizes, int n_in,
                              void* d_out, int out_size, void* d_ws, size_t ws_size,
                              hipStream_t stream) {
    const float* node_attrs = (const float*)d_in[0];
    const int*   edge_index = (const int*)d_in[1];
    const float* W_in      = (const float*)d_in[2];
    const float* a_src_in  = (const float*)d_in[3];
    const float* a_dst_in  = (const float*)d_in[4];
    const float* b_in      = (const float*)d_in[5];
    const float* W_mid     = (const float*)d_in[6];
    const float* a_src_mid = (const float*)d_in[7];
    const float* a_dst_mid = (const float*)d_in[8];
    const float* b_mid     = (const float*)d_in[9];
    const float* W_out     = (const float*)d_in[10];
    const float* a_src_out = (const float*)d_in[11];
    const float* a_dst_out = (const float*)d_in[12];
    const float* b_out     = (const float*)d_in[13];
    float* out = (float*)d_out;

    const int* srcArr = edge_index;
    const int* dstArr = edge_index + EE;

    char* w = (char*)d_ws;
    auto alloc = [&](size_t bytes) { void* p = (void*)w; w += (bytes + 255) & ~(size_t)255; return p; };
    int*   dst_ptr    = (int*)alloc((size_t)(NN + 1) * 4);
    int*   gcur       = (int*)alloc((size_t)NBUK * 4);
    int*   bucketBase = (int*)alloc((size_t)(NBUK + 1) * 4);
    int*   region     = (int*)alloc((size_t)NBUK * CAPB * 4);
    int*   esrc       = (int*)alloc((size_t)TOTE * 4);
    _Float16* xin16   = (_Float16*)alloc((size_t)NN * 128 * 2);
    _Float16* h       = (_Float16*)alloc((size_t)NN * 64 * 2);
    _Float16* x16     = (_Float16*)alloc((size_t)NN * 64 * 2);
    float* asrc       = (float*)alloc((size_t)NN * 2 * 4);
    float* adst       = (float*)alloc((size_t)NN * 2 * 4);
    float* ixbuf      = (float*)alloc((size_t)NN * 64 * 4);
    float* h_o        = (float*)alloc((size_t)NN * 4);
    float* asrc_o     = (float*)alloc((size_t)NN * 4);
    float* adst_o     = (float*)alloc((size_t)NN * 4);

    // CSR build
    hipMemsetAsync(gcur, 0, NBUK * 4, stream);
    binA<<<256, 256, 0, stream>>>(srcArr, dstArr, gcur, region);
    scan_buckets<<<1, 64, 0, stream>>>(gcur, bucketBase);
    binB<<<NBUK, 1024, 0, stream>>>(region, gcur, bucketBase, dst_ptr, esrc);

    // cast node_attrs to f16
    int n4 = NN * 128 / 4;
    cast_x<<<(n4 + 255) / 256, 256, 0, stream>>>(node_attrs, xin16, n4);

    int gemmBlocks = (NN + 63) / 64;
    int nodeBlocks = (NN + 3) / 4;

    // input layer
    gemm_attn<128><<<gemmBlocks, 256, 0, stream>>>(xin16, W_in, a_src_in, a_dst_in, h, asrc, adst);
    edge_agg<0><<<nodeBlocks, 256, 0, stream>>>(dst_ptr, esrc, h, asrc, adst, b_in, nullptr, ixbuf, x16);

    // 6 mid layers (shared weights)
    for (int l = 0; l < 6; ++l) {
        gemm_attn<64><<<gemmBlocks, 256, 0, stream>>>(x16, W_mid, a_src_mid, a_dst_mid, h, asrc, adst);
        edge_agg<1><<<nodeBlocks, 256, 0, stream>>>(dst_ptr, esrc, h, asrc, adst, b_mid, ixbuf, nullptr, x16);
    }

    // output layer
    gemm_out_attn<<<nodeBlocks, 256, 0, stream>>>(x16, W_out, a_src_out, a_dst_out, h_o, asrc_o, adst_o);
    edge_agg_out<<<nodeBlocks, 256, 0, stream>>>(dst_ptr, esrc, h_o, asrc_o, adst_o, b_out, out);
}

// Round 5
// 781.420 us; speedup vs baseline: 2.8288x; 1.0816x over previous
//
#include <hip/hip_runtime.h>
#include <hip/hip_fp16.h>
#include <cmath>

#define NN 100000
#define EE 1600000
#define TOTE (EE + NN)
#define SHIFT 10
#define NBUK 98          // ceil(NN / 1024)
#define CAPB 18432       // per-bucket region capacity; mean 17408 +7 sigma

typedef _Float16 half8_t __attribute__((ext_vector_type(8)));
typedef _Float16 half4_t __attribute__((ext_vector_type(4)));
typedef _Float16 half2_t __attribute__((ext_vector_type(2)));
typedef float float4_t __attribute__((ext_vector_type(4)));

__device__ __forceinline__ float lrelu(float v) { return v > 0.f ? v : 0.2f * v; }

// ---------------- CSR build: 2-phase bucket sort ----------------
// region entry packed: (src << 10) | (dst & 1023)
__global__ __launch_bounds__(256) void binA(const int* __restrict__ src, const int* __restrict__ dst,
                                            int* __restrict__ gcur, int* __restrict__ region) {
    __shared__ int cnt[NBUK], gbase[NBUK], pos[NBUK];
    int t = threadIdx.x;
    if (t < NBUK) cnt[t] = 0;
    __syncthreads();
    const int CH = (TOTE + gridDim.x - 1) / gridDim.x;
    int lo = blockIdx.x * CH;
    int hi = lo + CH; if (hi > TOTE) hi = TOTE;
    for (int e = lo + t; e < hi; e += 256) {
        int d = (e < EE) ? dst[e] : (e - EE);
        atomicAdd(&cnt[d >> SHIFT], 1);
    }
    __syncthreads();
    if (t < NBUK) {
        gbase[t] = atomicAdd(&gcur[t], cnt[t]);
        pos[t] = 0;
    }
    __syncthreads();
    for (int e = lo + t; e < hi; e += 256) {
        int s, d;
        if (e < EE) { s = src[e]; d = dst[e]; }
        else        { s = e - EE; d = s; }
        int b = d >> SHIFT;
        int k = atomicAdd(&pos[b], 1);
        region[(size_t)b * CAPB + gbase[b] + k] = (s << SHIFT) | (d & 1023);
    }
}

__global__ void scan_buckets(const int* __restrict__ gcur, int* __restrict__ bucketBase) {
    if (threadIdx.x == 0) {
        int run = 0;
        for (int b = 0; b < NBUK; ++b) { bucketBase[b] = run; run += gcur[b]; }
        bucketBase[NBUK] = run;
    }
}

__global__ __launch_bounds__(1024) void binB(const int* __restrict__ region, const int* __restrict__ gcur,
                                             const int* __restrict__ bucketBase,
                                             int* __restrict__ dst_ptr, int* __restrict__ esrc) {
    __shared__ int ncur[1024];
    __shared__ int wsum[16];
    int b = blockIdx.x, t = threadIdx.x;
    int n0 = b << SHIFT;
    int cntE = gcur[b];
    int base = bucketBase[b];
    const int* reg = region + (size_t)b * CAPB;
    ncur[t] = 0;
    __syncthreads();
    for (int i = t; i < cntE; i += 1024)
        atomicAdd(&ncur[reg[i] & 1023], 1);
    __syncthreads();
    int v = ncur[t];
    __syncthreads();
    int incl = v;
    for (int off = 1; off < 64; off <<= 1) {
        int u = __shfl_up(incl, off);
        if ((t & 63) >= off) incl += u;
    }
    if ((t & 63) == 63) wsum[t >> 6] = incl;
    __syncthreads();
    if (t < 16) {
        int w = wsum[t];
        int winc = w;
        for (int off = 1; off < 16; off <<= 1) {
            int u = __shfl_up(winc, off);
            if (t >= off) winc += u;
        }
        wsum[t] = winc - w;
    }
    __syncthreads();
    int excl = incl - v + wsum[t >> 6];
    int n = n0 + t;
    if (n < NN) dst_ptr[n] = base + excl;
    ncur[t] = base + excl;
    __syncthreads();
    for (int i = t; i < cntE; i += 1024) {
        int p = reg[i];
        int k = atomicAdd(&ncur[p & 1023], 1);
        esrc[k] = p >> SHIFT;
    }
    if (b == 0 && t == 0) dst_ptr[NN] = TOTE;
}

// ---------------- f32 -> f16 cast of node_attrs ----------------
__global__ __launch_bounds__(256) void cast_x(const float* __restrict__ in, _Float16* __restrict__ out, int n4) {
    int i = blockIdx.x * 256 + threadIdx.x;
    if (i >= n4) return;
    float4 v = ((const float4*)in)[i];
    half4_t h = { (_Float16)v.x, (_Float16)v.y, (_Float16)v.z, (_Float16)v.w };
    *(half4_t*)(out + 4 * (size_t)i) = h;
}

// ---------------- MFMA GEMM + fused attention coefficients ----------------
template <int K>
__global__ __launch_bounds__(256) void gemm_attn(const _Float16* __restrict__ X, const float* __restrict__ W,
                                                 const float* __restrict__ a_src, const float* __restrict__ a_dst,
                                                 _Float16* __restrict__ H, float* __restrict__ asrc,
                                                 float* __restrict__ adst) {
    __shared__ _Float16 wt[64][K + 8];    // wt[n][k], padded stride
    int t = threadIdx.x;
    for (int it = 0; it < K / 16; ++it) {
        int idx4 = it * 256 + t;
        int k = idx4 >> 4;
        int n4 = (idx4 * 4) & 63;
        float4 v = *(const float4*)(W + (size_t)idx4 * 4);
        wt[n4 + 0][k] = (_Float16)v.x;
        wt[n4 + 1][k] = (_Float16)v.y;
        wt[n4 + 2][k] = (_Float16)v.z;
        wt[n4 + 3][k] = (_Float16)v.w;
    }
    __syncthreads();

    int row0 = blockIdx.x * 64;
    int wr = (t >> 6) * 16;
    int lane = t & 63;
    int m = lane & 15;
    int q = lane >> 4;

    int rowA = row0 + wr + m;
    if (rowA >= NN) rowA = NN - 1;
    const _Float16* xrow = X + (size_t)rowA * K + q * 8;

    float4_t acc[4] = { {0,0,0,0}, {0,0,0,0}, {0,0,0,0}, {0,0,0,0} };
#pragma unroll
    for (int kc = 0; kc < K / 32; ++kc) {
        half8_t av = *(const half8_t*)(xrow + kc * 32);
#pragma unroll
        for (int c = 0; c < 4; ++c) {
            half8_t bv = *(const half8_t*)&wt[c * 16 + m][kc * 32 + q * 8];
            acc[c] = __builtin_amdgcn_mfma_f32_16x16x32_f16(av, bv, acc[c], 0, 0, 0);
        }
    }

#pragma unroll
    for (int r = 0; r < 4; ++r) {
        int row = row0 + wr + q * 4 + r;
        if (row < NN) {
#pragma unroll
            for (int c = 0; c < 4; ++c)
                H[(size_t)row * 64 + c * 16 + m] = (_Float16)acc[c][r];
        }
    }

    float as0 = a_src[m], as1 = a_src[16 + m], as2 = a_src[32 + m], as3 = a_src[48 + m];
    float ad0 = a_dst[m], ad1 = a_dst[16 + m], ad2 = a_dst[32 + m], ad3 = a_dst[48 + m];
#pragma unroll
    for (int r = 0; r < 4; ++r) {
        float s0 = acc[0][r] * as0 + acc[1][r] * as1;
        float s1 = acc[2][r] * as2 + acc[3][r] * as3;
        float d0 = acc[0][r] * ad0 + acc[1][r] * ad1;
        float d1 = acc[2][r] * ad2 + acc[3][r] * ad3;
#pragma unroll
        for (int mk = 1; mk < 16; mk <<= 1) {
            s0 += __shfl_xor(s0, mk);
            s1 += __shfl_xor(s1, mk);
            d0 += __shfl_xor(d0, mk);
            d1 += __shfl_xor(d1, mk);
        }
        int row = row0 + wr + q * 4 + r;
        if (m == 0 && row < NN) {
            asrc[2 * row + 0] = s0;
            asrc[2 * row + 1] = s1;
            adst[2 * row + 0] = d0;
            adst[2 * row + 1] = d1;
        }
    }
}

// ---------------- edge aggregation: flat softmax (clamped exp, no max pass) ----
// Wave per node. lane = eo*32 + c2: eo = edge parity, c2 = channel pair (2c2,2c2+1),
// head = c2>>4. 2 edges per step, 4 per unrolled iteration.
template <int MODE>
__global__ __launch_bounds__(256) void edge_agg(const int* __restrict__ dst_ptr, const int* __restrict__ esrc,
                                                const _Float16* __restrict__ h, const float* __restrict__ asrc,
                                                const float* __restrict__ adst, const float* __restrict__ bias,
                                                const float* __restrict__ init_in, float* __restrict__ init_out,
                                                _Float16* __restrict__ xout) {
    int n = (blockIdx.x * 256 + threadIdx.x) >> 6;
    if (n >= NN) return;
    int lane = threadIdx.x & 63;
    int eo = lane >> 5;
    int c2 = lane & 31;
    int head = c2 >> 4;
    int rs = dst_ptr[n], re = dst_ptr[n + 1];
    float adh = adst[2 * n + head];
    const _Float16* hb = h + 2 * c2;
    float acc0 = 0.f, acc1 = 0.f, l = 0.f;
    for (int i = rs; i < re; i += 4) {
        int iA = i + eo;
        int iB = i + 2 + eo;
        int sA = esrc[iA < re ? iA : re - 1];
        int sB = esrc[iB < re ? iB : re - 1];
        float eA = fminf(lrelu(asrc[2 * sA + head] + adh), 60.f);
        float eB = fminf(lrelu(asrc[2 * sB + head] + adh), 60.f);
        half2_t hA = *(const half2_t*)(hb + (size_t)sA * 64);
        half2_t hB = *(const half2_t*)(hb + (size_t)sB * 64);
        float pA = (iA < re) ? __expf(eA) : 0.f;
        float pB = (iB < re) ? __expf(eB) : 0.f;
        l += pA + pB;
        acc0 += pA * (float)hA[0] + pB * (float)hB[0];
        acc1 += pA * (float)hA[1] + pB * (float)hB[1];
    }
    // merge the two edge-parity halves
    acc0 += __shfl_xor(acc0, 32);
    acc1 += __shfl_xor(acc1, 32);
    l    += __shfl_xor(l, 32);
    if (eo == 0) {
        float inv = 1.f / l;
        float t0 = acc0 * inv + bias[2 * c2];
        float t1 = acc1 * inv + bias[2 * c2 + 1];
        if (MODE == 0) {
            *(float2*)(init_out + (size_t)n * 64 + 2 * c2) = make_float2(t0, t1);
        } else {
            float2 iv = *(const float2*)(init_in + (size_t)n * 64 + 2 * c2);
            t0 += iv.x; t1 += iv.y;
        }
        t0 = t0 > 0.f ? t0 : __expf(t0) - 1.f;
        t1 = t1 > 0.f ? t1 : __expf(t1) - 1.f;
        half2_t o = { (_Float16)t0, (_Float16)t1 };
        *(half2_t*)(xout + (size_t)n * 64 + 2 * c2) = o;
    }
}

// ---------------- output layer ----------------
__global__ __launch_bounds__(256) void gemm_out_attn(const _Float16* __restrict__ x, const float* __restrict__ Wout,
                                                     const float* __restrict__ a_s, const float* __restrict__ a_d,
                                                     float* __restrict__ h_o, float* __restrict__ asrc_o,
                                                     float* __restrict__ adst_o) {
    int n = (blockIdx.x * 256 + threadIdx.x) >> 6;
    if (n >= NN) return;
    int lane = threadIdx.x & 63;
    float v = (float)x[n * 64 + lane] * Wout[lane];
    for (int m = 32; m >= 1; m >>= 1) v += __shfl_xor(v, m);
    if (lane == 0) {
        h_o[n] = v;
        asrc_o[n] = v * a_s[0];
        adst_o[n] = v * a_d[0];
    }
}

__global__ __launch_bounds__(256) void edge_agg_out(const int* __restrict__ dst_ptr, const int* __restrict__ esrc,
                                                    const float* __restrict__ h_o, const float* __restrict__ asrc_o,
                                                    const float* __restrict__ adst_o, const float* __restrict__ b_out,
                                                    float* __restrict__ out) {
    int n = (blockIdx.x * 256 + threadIdx.x) >> 6;
    if (n >= NN) return;
    int lane = threadIdx.x & 63;
    int rs = dst_ptr[n], re = dst_ptr[n + 1];
    float adv = adst_o[n];
    float l = 0.f, acc = 0.f;
    for (int i = rs + lane; i < re; i += 64) {
        int s = esrc[i];
        float e = fminf(lrelu(asrc_o[s] + adv), 60.f);
        float p = __expf(e);
        l += p;
        acc = fmaf(p, h_o[s], acc);
    }
    for (int mm = 32; mm >= 1; mm >>= 1) {
        l += __shfl_xor(l, mm);
        acc += __shfl_xor(acc, mm);
    }
    if (lane == 0) out[n] = 1.f / (1.f + __expf(-(acc / l + b_out[0])));
}

// ---------------- launch ----------------
extern "C" void kernel_launch(void* const* d_in, const int* in_sizes, int n_in,
                              void* d_out, int out_size, void* d_ws, size_t ws_size,
                              hipStream_t stream) {
    const float* node_attrs = (const float*)d_in[0];
    const int*   edge_index = (const int*)d_in[1];
    const float* W_in      = (const float*)d_in[2];
    const float* a_src_in  = (const float*)d_in[3];
    const float* a_dst_in  = (const float*)d_in[4];
    const float* b_in      = (const float*)d_in[5];
    const float* W_mid     = (const float*)d_in[6];
    const float* a_src_mid = (const float*)d_in[7];
    const float* a_dst_mid = (const float*)d_in[8];
    const float* b_mid     = (const float*)d_in[9];
    const float* W_out     = (const float*)d_in[10];
    const float* a_src_out = (const float*)d_in[11];
    const float* a_dst_out = (const float*)d_in[12];
    const float* b_out     = (const float*)d_in[13];
    float* out = (float*)d_out;

    const int* srcArr = edge_index;
    const int* dstArr = edge_index + EE;

    char* w = (char*)d_ws;
    auto alloc = [&](size_t bytes) { void* p = (void*)w; w += (bytes + 255) & ~(size_t)255; return p; };
    int*   dst_ptr    = (int*)alloc((size_t)(NN + 1) * 4);
    int*   gcur       = (int*)alloc((size_t)NBUK * 4);
    int*   bucketBase = (int*)alloc((size_t)(NBUK + 1) * 4);
    int*   region     = (int*)alloc((size_t)NBUK * CAPB * 4);
    int*   esrc       = (int*)alloc((size_t)TOTE * 4);
    _Float16* xin16   = (_Float16*)alloc((size_t)NN * 128 * 2);
    _Float16* h       = (_Float16*)alloc((size_t)NN * 64 * 2);
    _Float16* x16     = (_Float16*)alloc((size_t)NN * 64 * 2);
    float* asrc       = (float*)alloc((size_t)NN * 2 * 4);
    float* adst       = (float*)alloc((size_t)NN * 2 * 4);
    float* ixbuf      = (float*)alloc((size_t)NN * 64 * 4);
    float* h_o        = (float*)alloc((size_t)NN * 4);
    float* asrc_o     = (float*)alloc((size_t)NN * 4);
    float* adst_o     = (float*)alloc((size_t)NN * 4);

    // CSR build
    hipMemsetAsync(gcur, 0, NBUK * 4, stream);
    binA<<<256, 256, 0, stream>>>(srcArr, dstArr, gcur, region);
    scan_buckets<<<1, 64, 0, stream>>>(gcur, bucketBase);
    binB<<<NBUK, 1024, 0, stream>>>(region, gcur, bucketBase, dst_ptr, esrc);

    // cast node_attrs to f16
    int n4 = NN * 128 / 4;
    cast_x<<<(n4 + 255) / 256, 256, 0, stream>>>(node_attrs, xin16, n4);

    int gemmBlocks = (NN + 63) / 64;
    int nodeBlocks = (NN + 3) / 4;

    // input layer
    gemm_attn<128><<<gemmBlocks, 256, 0, stream>>>(xin16, W_in, a_src_in, a_dst_in, h, asrc, adst);
    edge_agg<0><<<nodeBlocks, 256, 0, stream>>>(dst_ptr, esrc, h, asrc, adst, b_in, nullptr, ixbuf, x16);

    // 6 mid layers (shared weights)
    for (int l = 0; l < 6; ++l) {
        gemm_attn<64><<<gemmBlocks, 256, 0, stream>>>(x16, W_mid, a_src_mid, a_dst_mid, h, asrc, adst);
        edge_agg<1><<<nodeBlocks, 256, 0, stream>>>(dst_ptr, esrc, h, asrc, adst, b_mid, ixbuf, nullptr, x16);
    }

    // output layer
    gemm_out_attn<<<nodeBlocks, 256, 0, stream>>>(x16, W_out, a_src_out, a_dst_out, h_o, asrc_o, adst_o);
    edge_agg_out<<<nodeBlocks, 256, 0, stream>>>(dst_ptr, esrc, h_o, asrc_o, adst_o, b_out, out);
}